// Round 12
// baseline (97.250 us; speedup 1.0000x reference)
//
#include <hip/hip_runtime.h>

#define BTOT 65536
#define TST  28
#define PACK_DW 128
// ws layout (dwords): [0 .. 16384) packed frags (2 p x 64 lanes x 128)
//                     [16384 .. 20480) WxL: 32 x 128 f32 (rows 29..31 zeroed)
#define WXL_OFF 16384

typedef __attribute__((ext_vector_type(8)))  short bf16x8;
typedef __attribute__((ext_vector_type(4)))  float f32x4;
typedef __attribute__((ext_vector_type(16))) float f32x16;
typedef __attribute__((ext_vector_type(2)))  unsigned int u32x2;

__device__ __forceinline__ unsigned int f2bf(float f) {
    unsigned u = __float_as_uint(f);
    u += 0x7fff + ((u >> 16) & 1);   // RNE
    return u >> 16;
}
__device__ __forceinline__ unsigned int pk2bf(float a, float b) {
    return f2bf(a) | (f2bf(b) << 16);
}
__device__ __forceinline__ bf16x8 cvt8(f32x4 a, f32x4 b) {
    union { unsigned int u[4]; bf16x8 v; } r;
    asm("v_cvt_pk_bf16_f32 %0, %1, %2" : "=v"(r.u[0]) : "v"(a[0]), "v"(a[1]));
    asm("v_cvt_pk_bf16_f32 %0, %1, %2" : "=v"(r.u[1]) : "v"(a[2]), "v"(a[3]));
    asm("v_cvt_pk_bf16_f32 %0, %1, %2" : "=v"(r.u[2]) : "v"(b[0]), "v"(b[1]));
    asm("v_cvt_pk_bf16_f32 %0, %1, %2" : "=v"(r.u[3]) : "v"(b[2]), "v"(b[3]));
    return r.v;
}

// Fragment conventions (32x32x16, swapped orientation D = W^T . act^T):
//  A-frag (weights): elem j of frag ks = W^T[m = n0 + (lane&31)][k = ks*16 + (lane>>5)*8 + j]
//  B-frag (acts):    elem j of frag ks = act^T[k][batch = lane&31], same k decomposition
//  D:                col = lane&31 (batch), row = (reg&3) + 8*(reg>>2) + 4*(lane>>5)

// pack1: blocks 0..28 compute WxL row k (Wx = W1@W2a; row 28 = b2 + b1@W2a hit by
// x-frag element k=28 := 1.0; block 28 zeroes rows 29..31). Block 29 packs W2b
// A-frags (both p-halves, 2 n-tiles each). Block 30 packs W3 A-frags + b3
// D-layout init (p=0 region only — epilogue runs on the p==0 wave).
__global__ void pack1(const float* __restrict__ W1, const float* __restrict__ b1,
                      const float* __restrict__ W2, const float* __restrict__ b2,
                      const float* __restrict__ W3, const float* __restrict__ b3,
                      unsigned int* __restrict__ ws) {
    float* WxL = (float*)(ws + WXL_OFF);
    const int bid = blockIdx.x, tid = threadIdx.x;
    if (bid < 29) {
        const int k = bid, n = tid;   // 128 threads
        float s = 0.f;
        if (k < 28) {
            for (int m = 0; m < 128; ++m) s += W1[k * 128 + m] * W2[m * 128 + n];
        } else {
            s = b2[n];
            for (int m = 0; m < 128; ++m) s += b1[m] * W2[m * 128 + n];
        }
        WxL[k * 128 + n] = s;
        if (k == 28) { WxL[29*128+n] = 0.f; WxL[30*128+n] = 0.f; WxL[31*128+n] = 0.f; }
    } else if (bid == 29) {
        if (tid < 64) {
            const int hi = tid >> 5, ln = tid & 31;
            for (int p = 0; p < 2; ++p) {
                unsigned int* P = ws + (p * 64 + tid) * PACK_DW;
                for (int nt = 0; nt < 2; ++nt)
                    for (int ks = 0; ks < 8; ++ks)
                        for (int jd = 0; jd < 4; ++jd) {
                            const int k = 128 + ks * 16 + hi * 8 + jd * 2;
                            const int n = p * 64 + nt * 32 + ln;
                            P[(nt * 8 + ks) * 4 + jd] =
                                pk2bf(W2[k * 128 + n], W2[(k + 1) * 128 + n]);
                        }
            }
        }
    } else {
        if (tid < 64) {
            const int hi = tid >> 5, ln = tid & 31;
            unsigned int* P = ws + tid * PACK_DW;   // p=0 rows only
            for (int ks = 0; ks < 8; ++ks)
                for (int jd = 0; jd < 4; ++jd) {
                    const int k = ks * 16 + hi * 8 + jd * 2;
                    float lo = (ln < 10) ? W3[k * 10 + ln] : 0.f;
                    float hh = (ln < 10) ? W3[(k + 1) * 10 + ln] : 0.f;
                    P[80 + ks * 4 + jd] = pk2bf(lo, hh);
                }
            for (int reg = 0; reg < 16; ++reg) {
                const int row = (reg & 3) + 8 * (reg >> 2) + 4 * hi;
                P[112 + reg] = __float_as_uint((row < 10) ? b3[row] : 0.f);
            }
        }
    }
}

// pack2: Wx A-frags (K=32: ks=0,1), needs WxL from pack1's blocks 0..28.
__global__ void pack2(unsigned int* __restrict__ ws) {
    const int tid = threadIdx.x;
    if (tid < 64) {
        const float* WxL = (const float*)(ws + WXL_OFF);
        const int hi = tid >> 5, ln = tid & 31;
        for (int p = 0; p < 2; ++p) {
            unsigned int* P = ws + (p * 64 + tid) * PACK_DW;
            for (int nt = 0; nt < 2; ++nt)
                for (int ks = 0; ks < 2; ++ks)
                    for (int jd = 0; jd < 4; ++jd) {
                        const int k = ks * 16 + hi * 8 + jd * 2;
                        const int n = p * 64 + nt * 32 + ln;
                        P[64 + (nt * 2 + ks) * 4 + jd] =
                            pk2bf(WxL[k * 128 + n], WxL[(k + 1) * 128 + n]);
                    }
        }
    }
}

#define MFMA32(a, b, c) __builtin_amdgcn_mfma_f32_32x32x16_bf16(a, b, c, 0, 0, 0)

// Block = 2 waves = 1 team owning 32 batch rows; wave p owns n-half [64p,64p+64)
// as 2 n-tiles of 32. 32x32x16 MFMA: 20/wave-step for 32 rows (vs 20/16 rows
// with 16x16x32) at 1.20x the FLOP/cyc. H in frag-order LDS (r11-proven idea):
// uint idx = ks*260 + lane*4 + jd  (ks = k>>4 of next step's B-frag).
__global__ __launch_bounds__(128, 3) void rnn_kernel(
    const float* __restrict__ x, const unsigned int* __restrict__ wsPack,
    float* __restrict__ out)
{
    __shared__ __align__(16) unsigned int Hs[2][2080];   // 2 bufs x 8 ks x 260
    const int tid = threadIdx.x;
    const int p = tid >> 6, lane = tid & 63, hi = lane >> 5, ln = lane & 31;
    const int r0 = blockIdx.x * 32;

    const unsigned int* P = wsPack + (p * 64 + lane) * PACK_DW;
    bf16x8 w2b[2][8], wx[2][2];
    #pragma unroll
    for (int nt = 0; nt < 2; ++nt)
        #pragma unroll
        for (int ks = 0; ks < 8; ++ks)
            w2b[nt][ks] = *(const bf16x8*)(P + (nt * 8 + ks) * 4);
    #pragma unroll
    for (int nt = 0; nt < 2; ++nt)
        #pragma unroll
        for (int ks = 0; ks < 2; ++ks)
            wx[nt][ks] = *(const bf16x8*)(P + 64 + (nt * 2 + ks) * 4);

    // zero buf0
    #pragma unroll
    for (int i = 0; i < 17; ++i) {
        const int idx = tid + i * 128;
        if (idx < 2080) Hs[0][idx] = 0u;
    }
    __syncthreads();

    // x B-frags: frag ks covers x cols ks*16 + hi*8 + (0..7) of batch row ln.
    // Col 28 := 1.0 (bias hook into Wx row 28); cols 29..31 := 0.
    const f32x4 onec = {1.f, 0.f, 0.f, 0.f};
    const float* xr = x + (size_t)(r0 + ln) * 784 + hi * 8;
    f32x4 q0 = *(const f32x4*)xr;
    f32x4 q1 = *(const f32x4*)(xr + 4);
    f32x4 q2 = *(const f32x4*)(xr + 16);
    f32x4 q3 = onec;
    if (hi == 0) q3 = *(const f32x4*)(xr + 20);
    bf16x8 xb0 = cvt8(q0, q1);
    bf16x8 xb1 = cvt8(q2, q3);
    const f32x16 z16 = {0.f,0.f,0.f,0.f,0.f,0.f,0.f,0.f,0.f,0.f,0.f,0.f,0.f,0.f,0.f,0.f};

    int cur = 0;
    for (int t = 0; t < TST; ++t) {
        // x part first (covers h-read latency); bias rides in Wx row 28
        f32x16 acc0 = MFMA32(wx[0][0], xb0, z16);
        f32x16 acc1 = MFMA32(wx[1][0], xb0, z16);
        acc0 = MFMA32(wx[0][1], xb1, acc0);
        acc1 = MFMA32(wx[1][1], xb1, acc1);

        // prefetch next x under the MFMAs
        f32x4 n0v, n1v, n2v, n3v;
        const bool pf = (t + 1 < TST);
        if (pf) {
            const float* xp = xr + (t + 1) * 28;
            n0v = *(const f32x4*)xp;
            n1v = *(const f32x4*)(xp + 4);
            n2v = *(const f32x4*)(xp + 16);
            n3v = onec;
            if (hi == 0) n3v = *(const f32x4*)(xp + 20);
        }

        // h part: 8 K-steps, streamed 2-deep from frag-order LDS (lane-linear b128)
        bf16x8 hb = *(const bf16x8*)&Hs[cur][lane * 4];
        #pragma unroll
        for (int ks = 0; ks < 8; ++ks) {
            bf16x8 hbn;
            if (ks < 7) hbn = *(const bf16x8*)&Hs[cur][(ks + 1) * 260 + lane * 4];
            acc0 = MFMA32(w2b[0][ks], hb, acc0);
            acc1 = MFMA32(w2b[1][ks], hb, acc1);
            hb = hbn;
        }

        // relu + pack -> frag-order writes (one b64 per (nt,q))
        #pragma unroll
        for (int nt = 0; nt < 2; ++nt) {
            const int ntg = p * 2 + nt;
            #pragma unroll
            for (int q = 0; q < 4; ++q) {
                float f0, f1, f2, f3;
                if (nt == 0) {
                    f0 = acc0[4*q+0]; f1 = acc0[4*q+1]; f2 = acc0[4*q+2]; f3 = acc0[4*q+3];
                } else {
                    f0 = acc1[4*q+0]; f1 = acc1[4*q+1]; f2 = acc1[4*q+2]; f3 = acc1[4*q+3];
                }
                f0 = fmaxf(f0, 0.f); f1 = fmaxf(f1, 0.f);
                f2 = fmaxf(f2, 0.f); f3 = fmaxf(f3, 0.f);
                unsigned d0, d1;
                asm("v_cvt_pk_bf16_f32 %0, %1, %2" : "=v"(d0) : "v"(f0), "v"(f1));
                asm("v_cvt_pk_bf16_f32 %0, %1, %2" : "=v"(d1) : "v"(f2), "v"(f3));
                u32x2 st = {d0, d1};
                const int idx = (2 * ntg + (q >> 1)) * 260 + ((q & 1) * 32 + ln) * 4 + 2 * hi;
                *(u32x2*)&Hs[cur ^ 1][idx] = st;
            }
        }
        if (pf) { xb0 = cvt8(n0v, n1v); xb1 = cvt8(n2v, n3v); }
        __syncthreads();
        cur ^= 1;
    }

    // epilogue: p==0 wave computes the 32x32 out^T tile = W3^T.h^T + b3
    if (p == 0) {
        bf16x8 w3f[8];
        #pragma unroll
        for (int ks = 0; ks < 8; ++ks) w3f[ks] = *(const bf16x8*)(P + 80 + ks * 4);
        const float* bp = (const float*)(P + 112);
        f32x16 accO;
        #pragma unroll
        for (int r = 0; r < 16; ++r) accO[r] = bp[r];
        #pragma unroll
        for (int ks = 0; ks < 8; ++ks) {
            bf16x8 hb = *(const bf16x8*)&Hs[cur][ks * 260 + lane * 4];
            accO = MFMA32(w3f[ks], hb, accO);
        }
        float* op = out + (size_t)(r0 + ln) * 10;
        #pragma unroll
        for (int reg = 0; reg < 16; ++reg) {
            const int row = (reg & 3) + 8 * (reg >> 2) + 4 * hi;
            if (row < 10) op[row] = accO[reg];
        }
    }
}

extern "C" void kernel_launch(void* const* d_in, const int* in_sizes, int n_in,
                              void* d_out, int out_size, void* d_ws, size_t ws_size,
                              hipStream_t stream) {
    const float* x  = (const float*)d_in[0];
    const float* W1 = (const float*)d_in[1];
    const float* b1 = (const float*)d_in[2];
    const float* W2 = (const float*)d_in[3];
    const float* b2 = (const float*)d_in[4];
    const float* W3 = (const float*)d_in[5];
    const float* b3 = (const float*)d_in[6];
    unsigned int* ws = (unsigned int*)d_ws;   // 20480 dwords = 80 KiB

    pack1<<<31, 128, 0, stream>>>(W1, b1, W2, b2, W3, b3, ws);
    pack2<<<1, 64, 0, stream>>>(ws);
    rnn_kernel<<<BTOT / 32, 128, 0, stream>>>(x, ws, (float*)d_out);
}

// Round 13
// 79.402 us; speedup vs baseline: 1.2248x; 1.2248x over previous
//
#include <hip/hip_runtime.h>

#define BTOT 65536
#define TST  28
#define PACK_DW 100
// ws layout (dwords): [0 .. 12800) packed frags (2 p-variants x 64 lanes x 100)
//                     [12800 .. 16896) WxL: 32 x 128 f32 (rows 29..31 zeroed)
#define WXL_OFF 12800

typedef __attribute__((ext_vector_type(8))) short bf16x8;
typedef __attribute__((ext_vector_type(4))) float f32x4;
typedef __attribute__((ext_vector_type(2))) unsigned int u32x2;

__device__ __forceinline__ unsigned int f2bf(float f) {
    unsigned u = __float_as_uint(f);
    u += 0x7fff + ((u >> 16) & 1);   // RNE
    return u >> 16;
}
__device__ __forceinline__ unsigned int pk2bf(float a, float b) {
    return f2bf(a) | (f2bf(b) << 16);
}
__device__ __forceinline__ bf16x8 cvt8(f32x4 a, f32x4 b) {
    union { unsigned int u[4]; bf16x8 v; } r;
    asm("v_cvt_pk_bf16_f32 %0, %1, %2" : "=v"(r.u[0]) : "v"(a[0]), "v"(a[1]));
    asm("v_cvt_pk_bf16_f32 %0, %1, %2" : "=v"(r.u[1]) : "v"(a[2]), "v"(a[3]));
    asm("v_cvt_pk_bf16_f32 %0, %1, %2" : "=v"(r.u[2]) : "v"(b[0]), "v"(b[1]));
    asm("v_cvt_pk_bf16_f32 %0, %1, %2" : "=v"(r.u[3]) : "v"(b[2]), "v"(b[3]));
    return r.v;
}

// pack1: blocks 0..28 compute WxL row k (Wx = W1@W2a; row 28 = b2 + b1@W2a, the
// bias row hit by x-frag element k=28 := 1.0; block 28 also zeroes rows 29..31).
// Block 29 packs W2b A-frags (both p-halves); block 30 packs W3 frags + b3
// (p=0 rows only — the epilogue wave).
__global__ void pack1(const float* __restrict__ W1, const float* __restrict__ b1,
                      const float* __restrict__ W2, const float* __restrict__ b2,
                      const float* __restrict__ W3, const float* __restrict__ b3,
                      unsigned int* __restrict__ ws) {
    float* WxL = (float*)(ws + WXL_OFF);
    const int bid = blockIdx.x, tid = threadIdx.x;
    if (bid < 29) {
        const int k = bid, n = tid;   // 128 threads
        float s = 0.f;
        if (k < 28) {
            for (int m = 0; m < 128; ++m) s += W1[k * 128 + m] * W2[m * 128 + n];
        } else {
            s = b2[n];
            for (int m = 0; m < 128; ++m) s += b1[m] * W2[m * 128 + n];
        }
        WxL[k * 128 + n] = s;
        if (k == 28) { WxL[29*128+n] = 0.f; WxL[30*128+n] = 0.f; WxL[31*128+n] = 0.f; }
    } else if (bid == 29) {
        if (tid < 64) {
            const int lr = tid & 15, kh = tid >> 4;
            for (int p = 0; p < 2; ++p) {
                unsigned int* P = ws + (p * 64 + tid) * PACK_DW;
                for (int kk = 0; kk < 4; ++kk)
                    for (int t = 0; t < 4; ++t)
                        for (int jd = 0; jd < 4; ++jd) {
                            const int k = 128 + kk * 32 + kh * 8 + jd * 2;
                            const int n = p * 64 + t * 16 + lr;
                            P[(kk * 4 + t) * 4 + jd] =
                                pk2bf(W2[k * 128 + n], W2[(k + 1) * 128 + n]);
                        }
            }
        }
    } else {
        if (tid < 64) {
            const int lr = tid & 15, kh = tid >> 4;
            unsigned int* P = ws + tid * PACK_DW;   // p=0 rows only
            for (int kk = 0; kk < 4; ++kk)
                for (int jd = 0; jd < 4; ++jd) {
                    const int k = kk * 32 + kh * 8 + jd * 2;
                    float lo = (lr < 10) ? W3[k * 10 + lr] : 0.f;
                    float hi = (lr < 10) ? W3[(k + 1) * 10 + lr] : 0.f;
                    P[80 + kk * 4 + jd] = pk2bf(lo, hi);
                }
            for (int j = 0; j < 4; ++j) {
                const int o = kh * 4 + j;
                P[96 + j] = __float_as_uint((o < 10) ? b3[o] : 0.f);
            }
        }
    }
}

// pack2: Wx A-frags (needs WxL from pack1's blocks 0..28).
__global__ void pack2(unsigned int* __restrict__ ws) {
    const int tid = threadIdx.x;
    if (tid < 64) {
        const float* WxL = (const float*)(ws + WXL_OFF);
        const int lr = tid & 15, kh = tid >> 4;
        for (int p = 0; p < 2; ++p) {
            unsigned int* P = ws + (p * 64 + tid) * PACK_DW;
            for (int t = 0; t < 4; ++t)
                for (int jd = 0; jd < 4; ++jd) {
                    const int k = kh * 8 + jd * 2, n = p * 64 + t * 16 + lr;
                    P[64 + t * 4 + jd] = pk2bf(WxL[k * 128 + n], WxL[(k + 1) * 128 + n]);
                }
        }
    }
}

// Round-11 structure (best: 80.4us) with ONE change: the per-step barrier is a
// raw s_barrier preceded only by lgkmcnt(0) (LDS-write visibility). This keeps
// the x-prefetch global loads IN FLIGHT across the barrier — __syncthreads
// would drain vmcnt(0) every step, pinning each step at HBM latency.
// H stored in B-FRAG ORDER: uint index kk*256+kh*64+lr*4+jd; reads lane-linear.
__global__ __launch_bounds__(256, 3) void rnn_kernel(
    const float* __restrict__ x, const unsigned int* __restrict__ wsPack,
    float* __restrict__ out)
{
    __shared__ __align__(16) unsigned int Hs[2][2][1024];  // [team][buf][frag-order]
    const int tid = threadIdx.x;
    const int w = tid >> 6, lane = tid & 63, lr = lane & 15, kh = lane >> 4;
    const int g = w >> 1, p = w & 1;
    const int r0 = blockIdx.x * 32 + g * 16;

    const unsigned int* P = wsPack + (p * 64 + lane) * PACK_DW;
    bf16x8 w2b[4][4], wx[4];
    #pragma unroll
    for (int kk = 0; kk < 4; ++kk)
        #pragma unroll
        for (int t = 0; t < 4; ++t)
            w2b[kk][t] = *(const bf16x8*)(P + (kk * 4 + t) * 4);
    #pragma unroll
    for (int t = 0; t < 4; ++t) wx[t] = *(const bf16x8*)(P + 64 + t * 4);

    // write-address constants per (p, t4, kh): hidden base q0 = p*64+t4*16+kh*4
    //   kkW = p*2 + (t4>>1); khR = (t4*2 + (kh>>1)) & 3; jd = 2*(kh&1)
    unsigned wAddr[4];
    #pragma unroll
    for (int t4 = 0; t4 < 4; ++t4) {
        const int kkW = p * 2 + (t4 >> 1);
        const int khR = (t4 * 2 + (kh >> 1)) & 3;
        const int jd  = (kh & 1) * 2;
        wAddr[t4] = kkW * 256 + khR * 64 + lr * 4 + jd;
    }

    // zero buf0 of both teams (2 x 1024 uints)
    #pragma unroll
    for (int i = 0; i < 4; ++i) {
        Hs[0][0][tid + i * 256] = 0u;
        Hs[1][0][tid + i * 256] = 0u;
    }
    __syncthreads();

    // x B-frag: lane (kh,lr) reads x[r0+lr][28t + 8kh + j]; kh==3 upper half is
    // {1.0 (k=28 bias hook), 0,0,0} — Wx rows 29..31 are zero.
    const f32x4 onec = {1.f, 0.f, 0.f, 0.f};
    const float* xr = x + (size_t)(r0 + lr) * 784 + 8 * kh;
    f32x4 xa = *(const f32x4*)xr;
    f32x4 xc = (kh < 3) ? *(const f32x4*)(xr + 4) : onec;
    bf16x8 xb = cvt8(xa, xc);
    const f32x4 z4 = {0.f, 0.f, 0.f, 0.f};

    int cur = 0;
    for (int t = 0; t < TST; ++t) {
        // issue next-x load FIRST: issue->use distance ~ one full step, and the
        // raw barrier below no longer drains it.
        f32x4 na, nc;
        const bool pf = (t + 1 < TST);
        if (pf) {
            const float* xp = xr + (t + 1) * 28;
            na = *(const f32x4*)xp;
            nc = (kh < 3) ? *(const f32x4*)(xp + 4) : onec;
        }

        f32x4 acc[4];
        // x part (bias rides in Wx row 28)
        #pragma unroll
        for (int t4 = 0; t4 < 4; ++t4)
            acc[t4] = __builtin_amdgcn_mfma_f32_16x16x32_bf16(wx[t4], xb, z4, 0, 0, 0);
        // h B-frags: lane-linear b128 reads (zero conflicts)
        bf16x8 hbv[4];
        #pragma unroll
        for (int kk = 0; kk < 4; ++kk)
            hbv[kk] = *(const bf16x8*)&Hs[g][cur][kk * 256 + lane * 4];
        #pragma unroll
        for (int kk = 0; kk < 4; ++kk)
            #pragma unroll
            for (int t4 = 0; t4 < 4; ++t4)
                acc[t4] = __builtin_amdgcn_mfma_f32_16x16x32_bf16(w2b[kk][t4], hbv[kk], acc[t4], 0, 0, 0);
        // relu + pack -> one b64 store per t4 into frag-order slots (<=2-way)
        #pragma unroll
        for (int t4 = 0; t4 < 4; ++t4) {
            f32x4 v = acc[t4];
            v[0] = fmaxf(v[0], 0.f); v[1] = fmaxf(v[1], 0.f);
            v[2] = fmaxf(v[2], 0.f); v[3] = fmaxf(v[3], 0.f);
            unsigned lo, hi;
            asm("v_cvt_pk_bf16_f32 %0, %1, %2" : "=v"(lo) : "v"(v[0]), "v"(v[1]));
            asm("v_cvt_pk_bf16_f32 %0, %1, %2" : "=v"(hi) : "v"(v[2]), "v"(v[3]));
            u32x2 st = {lo, hi};
            *(u32x2*)&Hs[g][cur ^ 1][wAddr[t4]] = st;
        }
        if (pf) xb = cvt8(na, nc);
        // raw barrier: order LDS (lgkmcnt) but leave global loads in flight
        asm volatile("s_waitcnt lgkmcnt(0)\n\ts_barrier" ::: "memory");
        cur ^= 1;
    }

    // epilogue: p==0 wave of each team computes out^T = W3^T.h^T + b3
    if (p == 0) {
        bf16x8 w3f[4];
        #pragma unroll
        for (int kk = 0; kk < 4; ++kk) w3f[kk] = *(const bf16x8*)(P + 80 + kk * 4);
        const float* bp = (const float*)(P + 96);
        f32x4 accO = {bp[0], bp[1], bp[2], bp[3]};
        #pragma unroll
        for (int kk = 0; kk < 4; ++kk) {
            bf16x8 hb = *(const bf16x8*)&Hs[g][cur][kk * 256 + lane * 4];
            accO = __builtin_amdgcn_mfma_f32_16x16x32_bf16(w3f[kk], hb, accO, 0, 0, 0);
        }
        float* op = out + (size_t)(r0 + lr) * 10 + kh * 4;
        #pragma unroll
        for (int j = 0; j < 4; ++j)
            if (kh * 4 + j < 10) op[j] = accO[j];
    }
}

extern "C" void kernel_launch(void* const* d_in, const int* in_sizes, int n_in,
                              void* d_out, int out_size, void* d_ws, size_t ws_size,
                              hipStream_t stream) {
    const float* x  = (const float*)d_in[0];
    const float* W1 = (const float*)d_in[1];
    const float* b1 = (const float*)d_in[2];
    const float* W2 = (const float*)d_in[3];
    const float* b2 = (const float*)d_in[4];
    const float* W3 = (const float*)d_in[5];
    const float* b3 = (const float*)d_in[6];
    unsigned int* ws = (unsigned int*)d_ws;   // 16896 dwords = 66 KiB

    pack1<<<31, 128, 0, stream>>>(W1, b1, W2, b2, W3, b3, ws);
    pack2<<<1, 64, 0, stream>>>(ws);
    rnn_kernel<<<BTOT / 32, 256, 0, stream>>>(x, ws, (float*)d_out);
}